// Round 6
// baseline (293.639 us; speedup 1.0000x reference)
//
#include <hip/hip_runtime.h>
#include <hip/hip_bf16.h>
#include <math.h>

#define ND 128      // feature dim D
#define NH 4        // heads
#define HD 512      // H*D

typedef __attribute__((ext_vector_type(8))) short bf16x8;
typedef __attribute__((ext_vector_type(4))) float f32x4;

__device__ __forceinline__ unsigned pack_bf16(float a, float b) {
    unsigned ua = __float_as_uint(a), ub = __float_as_uint(b);
    ua = (ua + 0x7fffu + ((ua >> 16) & 1u)) >> 16;
    ub = (ub + 0x7fffu + ((ub >> 16) & 1u)) >> 16;
    return ua | (ub << 16);
}
__device__ __forceinline__ unsigned short bf16r(float a) {
    unsigned ua = __float_as_uint(a);
    return (unsigned short)((ua + 0x7fffu + ((ua >> 16) & 1u)) >> 16);
}
__device__ __forceinline__ float bflo(unsigned u) { return __uint_as_float(u << 16); }
__device__ __forceinline__ float bfhi(unsigned u) { return __uint_as_float(u & 0xffff0000u); }

// ---------------------------------------------------------------------------
// K0: fused W-transpose (blocks [0,256)) + dst histogram (blocks [256, ...)).
// ---------------------------------------------------------------------------
__global__ __launch_bounds__(256) void prep_and_hist(const float* __restrict__ W,
                                                     unsigned short* __restrict__ Wt,
                                                     const int* __restrict__ dst,
                                                     int* __restrict__ cnt, int ne) {
    if (blockIdx.x < 256) {
        int idx = blockIdx.x * 256 + threadIdx.x;   // over 512*128
        int nl = idx >> 7, k = idx & 127;
        Wt[idx] = bf16r(W[(size_t)k * HD + nl]);
    } else {
        int e = (blockIdx.x - 256) * 256 + threadIdx.x;
        if (e < ne) atomicAdd(&cnt[dst[e]], 1);
    }
}

// ---------------------------------------------------------------------------
// K1: MFMA GEMM. Block = 128 rows x 128 cols (one head), 4 waves.
// A: x fp32 -> bf16 LDS (swizzled). B: Wt bf16 -> LDS (swizzled).
// Epilogue: fp32 attention dots from acc; xw store repacked via LDS so the
// global stores are coalesced dwordx4.
// ---------------------------------------------------------------------------
__global__ __launch_bounds__(256, 2) void gemm_mfma(
        const float* __restrict__ x, const unsigned short* __restrict__ Wt,
        const float* __restrict__ att_src, const float* __restrict__ att_dst,
        unsigned short* __restrict__ xw, float* __restrict__ a_src,
        float* __restrict__ a_dst, int n) {
    __shared__ char lds[65536];
    char* As = lds;            // 128 rows x 128 k bf16, swizzled
    char* Bs = lds + 32768;    // 128 n   x 128 k bf16, swizzled
    const int t = threadIdx.x;
    const int row0 = blockIdx.x * 128;
    const int h = blockIdx.y;
    const int l = t & 63, w = t >> 6;
    const int eid = l & 15, g = l >> 4;

    // stage A
#pragma unroll
    for (int i = 0; i < 8; ++i) {
        int c = t + i * 256;
        int m = c >> 4, kb = c & 15;
        int row = row0 + m;
        uint4 pk;
        if (row < n) {
            const float4* xp = (const float4*)(x + (size_t)row * ND + kb * 8);
            float4 f0 = xp[0], f1 = xp[1];
            pk.x = pack_bf16(f0.x, f0.y); pk.y = pack_bf16(f0.z, f0.w);
            pk.z = pack_bf16(f1.x, f1.y); pk.w = pack_bf16(f1.z, f1.w);
        } else { pk.x = pk.y = pk.z = pk.w = 0u; }
        *(uint4*)(As + m * 256 + ((kb * 16) ^ ((m & 7) << 4))) = pk;
    }
    // stage B
#pragma unroll
    for (int i = 0; i < 8; ++i) {
        int c = t + i * 256;
        int nl = c >> 4, kb = c & 15;
        uint4 pv = *(const uint4*)(Wt + (size_t)(h * 128 + nl) * 128 + kb * 8);
        *(uint4*)(Bs + nl * 256 + ((kb * 16) ^ ((nl & 7) << 4))) = pv;
    }
    __syncthreads();

    f32x4 acc[2][8];
#pragma unroll
    for (int mt = 0; mt < 2; ++mt)
#pragma unroll
        for (int nr = 0; nr < 8; ++nr) acc[mt][nr] = (f32x4){0.f, 0.f, 0.f, 0.f};

    const int swz = (eid & 7) << 4;
#pragma unroll
    for (int ks = 0; ks < 4; ++ks) {
        int koff = (ks * 64 + g * 16) ^ swz;
        bf16x8 a0 = *(const bf16x8*)(As + (w * 32 + eid) * 256 + koff);
        bf16x8 a1 = *(const bf16x8*)(As + (w * 32 + 16 + eid) * 256 + koff);
#pragma unroll
        for (int nr = 0; nr < 8; ++nr) {
            bf16x8 b = *(const bf16x8*)(Bs + (nr * 16 + eid) * 256 + koff);
            acc[0][nr] = __builtin_amdgcn_mfma_f32_16x16x32_bf16(a0, b, acc[0][nr], 0, 0, 0);
            acc[1][nr] = __builtin_amdgcn_mfma_f32_16x16x32_bf16(a1, b, acc[1][nr], 0, 0, 0);
        }
    }

    // epilogue A: attention dots from fp32 acc (register+shfl only)
    float asv[8], adv[8];
#pragma unroll
    for (int nr = 0; nr < 8; ++nr) {
        asv[nr] = att_src[h * ND + nr * 16 + eid];
        adv[nr] = att_dst[h * ND + nr * 16 + eid];
    }
#pragma unroll
    for (int mt = 0; mt < 2; ++mt) {
#pragma unroll
        for (int ri = 0; ri < 4; ++ri) {
            float s = 0.f, d = 0.f;
#pragma unroll
            for (int nr = 0; nr < 8; ++nr) {
                s += acc[mt][nr][ri] * asv[nr];
                d += acc[mt][nr][ri] * adv[nr];
            }
#pragma unroll
            for (int off = 1; off < 16; off <<= 1) {
                s += __shfl_xor(s, off);
                d += __shfl_xor(d, off);
            }
            int row = row0 + w * 32 + mt * 16 + g * 4 + ri;
            if (eid == 0 && row < n) {
                a_src[(size_t)row * NH + h] = s;
                a_dst[(size_t)row * NH + h] = d;
            }
        }
    }

    // epilogue B: repack C tile through LDS -> coalesced bf16 stores
    __syncthreads();   // all waves done reading As/Bs
    unsigned short* Ps = (unsigned short*)lds;   // [128 rows][128 cols]
#pragma unroll
    for (int mt = 0; mt < 2; ++mt)
#pragma unroll
        for (int ri = 0; ri < 4; ++ri) {
            int rl = w * 32 + mt * 16 + g * 4 + ri;
#pragma unroll
            for (int nr = 0; nr < 8; ++nr)
                Ps[rl * 128 + nr * 16 + eid] = bf16r(acc[mt][nr][ri]);
        }
    __syncthreads();
#pragma unroll
    for (int i = 0; i < 8; ++i) {
        int row = i * 16 + (t >> 4);
        int grow = row0 + row;
        if (grow < n) {
            uint4 v = *(const uint4*)(Ps + row * 128 + (t & 15) * 8);
            *(uint4*)(xw + (size_t)grow * HD + h * ND + (t & 15) * 8) = v;
        }
    }
}

// ---------------------------------------------------------------------------
// Counting-sort scans + scatter.
// ---------------------------------------------------------------------------
__global__ __launch_bounds__(256) void scanA(const int* __restrict__ cnt,
                                             int* __restrict__ partial,
                                             int* __restrict__ bsum, int n) {
    __shared__ int sh[256];
    int gid = blockIdx.x * 256 + threadIdx.x;
    int v = (gid < n) ? cnt[gid] : 0;
    int val = v;
    sh[threadIdx.x] = val;
    __syncthreads();
#pragma unroll
    for (int off = 1; off < 256; off <<= 1) {
        int add = (threadIdx.x >= off) ? sh[threadIdx.x - off] : 0;
        __syncthreads();
        val += add;
        sh[threadIdx.x] = val;
        __syncthreads();
    }
    if (gid < n) partial[gid] = val - v;
    if (threadIdx.x == 255) bsum[blockIdx.x] = val;
}

__global__ __launch_bounds__(256) void scanB(int* __restrict__ bsum, int nb) {
    __shared__ int sh[256];
    int t = threadIdx.x;
    int v = (t < nb) ? bsum[t] : 0;
    int val = v;
    sh[t] = val;
    __syncthreads();
#pragma unroll
    for (int off = 1; off < 256; off <<= 1) {
        int add = (t >= off) ? sh[t - off] : 0;
        __syncthreads();
        val += add;
        sh[t] = val;
        __syncthreads();
    }
    if (t < nb) bsum[t] = val - v;
}

__global__ __launch_bounds__(256) void scanC(const int* __restrict__ partial,
                                             const int* __restrict__ bsum,
                                             int* __restrict__ starts,
                                             int* __restrict__ cursor, int n, int ne) {
    int gid = blockIdx.x * 256 + threadIdx.x;
    if (gid < n) {
        int s = partial[gid] + bsum[blockIdx.x];
        starts[gid] = s;
        cursor[gid] = s;
    }
    if (gid == 0) starts[n] = ne;
}

__global__ __launch_bounds__(256) void scatter_edges(const int* __restrict__ src,
                                                     const int* __restrict__ dst,
                                                     int* __restrict__ cursor,
                                                     int* __restrict__ srcperm, int ne) {
    int e = blockIdx.x * 256 + threadIdx.x;
    if (e < ne) {
        int pos = atomicAdd(&cursor[dst[e]], 1);
        srcperm[pos] = src[e];
    }
}

// ---------------------------------------------------------------------------
// K_agg: TWO waves per dst node (each a contiguous half of the edge segment),
// 16-edge chunks; lane = (head=l>>4, slot=l&15); 4-deep gather batches (keeps
// VGPR ~36 so occupancy stays high — R5's 8-deep batch halved occupancy).
// Partials combined via LDS; wave 0 of each pair does the LN/GELU epilogue.
// ---------------------------------------------------------------------------
#define ACC8(vv, ww)                                                      \
    acc[0] = fmaf(ww, bflo(vv.x), acc[0]);                                \
    acc[1] = fmaf(ww, bfhi(vv.x), acc[1]);                                \
    acc[2] = fmaf(ww, bflo(vv.y), acc[2]);                                \
    acc[3] = fmaf(ww, bfhi(vv.y), acc[3]);                                \
    acc[4] = fmaf(ww, bflo(vv.z), acc[4]);                                \
    acc[5] = fmaf(ww, bfhi(vv.z), acc[5]);                                \
    acc[6] = fmaf(ww, bflo(vv.w), acc[6]);                                \
    acc[7] = fmaf(ww, bfhi(vv.w), acc[7]);

#define GATHER4(J)                                                        \
    { int t0 = __shfl(sl, (J)+0), t1 = __shfl(sl, (J)+1),                 \
          t2 = __shfl(sl, (J)+2), t3 = __shfl(sl, (J)+3);                 \
      uint4 v0 = xw[(size_t)t0 * 64 + lane];                              \
      uint4 v1 = xw[(size_t)t1 * 64 + lane];                              \
      uint4 v2 = xw[(size_t)t2 * 64 + lane];                              \
      uint4 v3 = xw[(size_t)t3 * 64 + lane];                              \
      float w0 = __shfl(em, hb+(J)+0), w1 = __shfl(em, hb+(J)+1),         \
            w2 = __shfl(em, hb+(J)+2), w3 = __shfl(em, hb+(J)+3);         \
      ACC8(v0, w0); ACC8(v1, w1); ACC8(v2, w2); ACC8(v3, w3); }

#define GATHER2(J)                                                        \
    { int t0 = __shfl(sl, (J)+0), t1 = __shfl(sl, (J)+1);                 \
      uint4 v0 = xw[(size_t)t0 * 64 + lane];                              \
      uint4 v1 = xw[(size_t)t1 * 64 + lane];                              \
      float w0 = __shfl(em, hb+(J)+0), w1 = __shfl(em, hb+(J)+1);         \
      ACC8(v0, w0); ACC8(v1, w1); }

#define GATHER1(J)                                                        \
    { int t0 = __shfl(sl, (J));                                           \
      uint4 v0 = xw[(size_t)t0 * 64 + lane];                              \
      float w0 = __shfl(em, hb+(J));                                      \
      ACC8(v0, w0); }

__global__ __launch_bounds__(256) void node_agg(const int* __restrict__ srcperm,
                                                const int* __restrict__ starts,
                                                const float* __restrict__ a_src,
                                                const float* __restrict__ a_dst,
                                                const uint4* __restrict__ xw,
                                                const float* __restrict__ x,
                                                const float* __restrict__ bias,
                                                const float* __restrict__ gamma,
                                                const float* __restrict__ beta,
                                                float* __restrict__ out, int n) {
    __shared__ float comb[2][64][9];   // wave-1 partials (acc[8], den)

    const int pair = threadIdx.x >> 7;        // which node within block
    const int q    = (threadIdx.x >> 6) & 1;  // wave within pair
    const int lane = threadIdx.x & 63;
    const int node = blockIdx.x * 2 + pair;
    const bool alive = (node < n);
    const int hgrp = lane >> 4;
    const int eid = lane & 15;
    const int hb = hgrp << 4;

    int s0 = 0, s1 = 0;
    float ad_m = 0.f;
    if (alive) {
        s0 = starts[node]; s1 = starts[node + 1];
        ad_m = a_dst[(size_t)node * NH + hgrp];
    }
    // contiguous half split between the two waves of the pair
    int d = s1 - s0;
    int half = (d + 1) >> 1;
    int lo = s0 + q * half;
    int hi = q ? s1 : s0 + half;

    float den = 0.f;
    float acc[8];
#pragma unroll
    for (int j = 0; j < 8; ++j) acc[j] = 0.f;

    for (int base = lo; base < hi; base += 16) {
        int rem = hi - base; if (rem > 16) rem = 16;
        int sl = 0; float em = 0.f;
        if (eid < rem) {
            sl = srcperm[base + eid];
            float A = a_src[(size_t)sl * NH + hgrp] + ad_m;
            A = (A > 0.f) ? A : 0.2f * A;
            em = expf(A);
        }
        den += em;

        if (rem == 16) {
            GATHER4(0); GATHER4(4); GATHER4(8); GATHER4(12);
        } else {
            int jj = 0;
            while (jj + 4 <= rem) { GATHER4(jj); jj += 4; }
            if (jj + 2 <= rem) { GATHER2(jj); jj += 2; }
            if (jj < rem)      { GATHER1(jj); }
        }
    }

    // wave-1 deposits partials; wave-0 combines
    if (q == 1) {
#pragma unroll
        for (int j = 0; j < 8; ++j) comb[pair][lane][j] = acc[j];
        comb[pair][lane][8] = den;
    }
    __syncthreads();
    if (q == 1 || !alive) return;
#pragma unroll
    for (int j = 0; j < 8; ++j) acc[j] += comb[pair][lane][j];
    den += comb[pair][lane][8];

    // per-head denominator: reduce over the 16 slots in my head group
#pragma unroll
    for (int off = 1; off < 16; off <<= 1) den += __shfl_xor(den, off);
    float imy = (den > 0.f) ? 0.25f / den : 0.f;

    float v[8];
#pragma unroll
    for (int j = 0; j < 8; ++j) {
        v[j] = acc[j] * imy;
        v[j] += __shfl_xor(v[j], 16);   // sum over heads
        v[j] += __shfl_xor(v[j], 32);
    }

    const float4* bp = (const float4*)(bias + eid * 8);
    float4 b0 = bp[0], b1 = bp[1];
    v[0] += b0.x; v[1] += b0.y; v[2] += b0.z; v[3] += b0.w;
    v[4] += b1.x; v[5] += b1.y; v[6] += b1.z; v[7] += b1.w;

    // LayerNorm over 128 features = 16 lane-groups x 8 slots (replicated 4x)
    float s = 0.f, s2 = 0.f;
#pragma unroll
    for (int j = 0; j < 8; ++j) { s += v[j]; s2 += v[j] * v[j]; }
#pragma unroll
    for (int off = 1; off < 16; off <<= 1) {
        s += __shfl_xor(s, off);
        s2 += __shfl_xor(s2, off);
    }
    float mu = s * (1.0f / ND);
    float var = s2 * (1.0f / ND) - mu * mu;
    var = fmaxf(var, 0.0f);
    float inv = rsqrtf(var + 1e-5f);

    const float4* gp = (const float4*)(gamma + eid * 8);
    const float4* btp = (const float4*)(beta + eid * 8);
    float4 g0 = gp[0], g1 = gp[1];
    float4 t0 = btp[0], t1 = btp[1];
    float gm[8] = {g0.x, g0.y, g0.z, g0.w, g1.x, g1.y, g1.z, g1.w};
    float bt[8] = {t0.x, t0.y, t0.z, t0.w, t1.x, t1.y, t1.z, t1.w};

    float y[8];
#pragma unroll
    for (int j = 0; j < 8; ++j) {
        float yn = (v[j] - mu) * inv * gm[j] + bt[j];
        y[j] = 0.5f * yn * (1.0f + erff(yn * 0.70710678118654752f));
    }

    if (lane < 16) {   // one replica writes; +residual
        const float4* xp = (const float4*)(x + (size_t)node * ND + eid * 8);
        float4 r0 = xp[0], r1 = xp[1];
        float4 o0 = {y[0] + r0.x, y[1] + r0.y, y[2] + r0.z, y[3] + r0.w};
        float4 o1 = {y[4] + r1.x, y[5] + r1.y, y[6] + r1.z, y[7] + r1.w};
        float4* op = (float4*)(out + (size_t)node * ND + eid * 8);
        op[0] = o0; op[1] = o1;
    }
}

// ---------------------------------------------------------------------------
extern "C" void kernel_launch(void* const* d_in, const int* in_sizes, int n_in,
                              void* d_out, int out_size, void* d_ws, size_t ws_size,
                              hipStream_t stream) {
    const float* x       = (const float*)d_in[0];
    const int*   edge    = (const int*)d_in[1];   // [2, E]: src row then dst row
    const float* W       = (const float*)d_in[2];
    const float* att_src = (const float*)d_in[3];
    const float* att_dst = (const float*)d_in[4];
    const float* bias    = (const float*)d_in[5];
    const float* gamma   = (const float*)d_in[6];
    const float* beta    = (const float*)d_in[7];
    float* out = (float*)d_out;

    const int n  = in_sizes[0] / ND;   // 50000
    const int ne = in_sizes[1] / 2;    // 800000
    const int* src = edge;
    const int* dst = edge + ne;

    const int nb = (n + 255) / 256;

    char* wsp = (char*)d_ws;
    unsigned short* xw = (unsigned short*)wsp;  wsp += (size_t)n * HD * sizeof(short);
    unsigned short* Wt = (unsigned short*)wsp;  wsp += (size_t)HD * ND * sizeof(short);
    float* a_src   = (float*)wsp;               wsp += (size_t)n * NH * sizeof(float);
    float* a_dst   = (float*)wsp;               wsp += (size_t)n * NH * sizeof(float);
    int*   cnt     = (int*)wsp;                 wsp += (size_t)n * sizeof(int);
    int*   partial = (int*)wsp;                 wsp += (size_t)n * sizeof(int);
    int*   bsum    = (int*)wsp;                 wsp += 256 * sizeof(int);
    int*   starts  = (int*)wsp;                 wsp += (size_t)(n + 1) * sizeof(int);
    int*   cursor  = (int*)wsp;                 wsp += (size_t)n * sizeof(int);
    int*   srcperm = (int*)wsp;                 wsp += (size_t)ne * sizeof(int);

    hipMemsetAsync(cnt, 0, (size_t)n * sizeof(int), stream);

    prep_and_hist<<<256 + (ne + 255) / 256, 256, 0, stream>>>(W, Wt, dst, cnt, ne);

    dim3 ggrid((n + 127) / 128, NH);
    gemm_mfma<<<ggrid, 256, 0, stream>>>(x, Wt, att_src, att_dst, xw, a_src, a_dst, n);

    scanA<<<nb, 256, 0, stream>>>(cnt, partial, bsum, n);
    scanB<<<1, 256, 0, stream>>>(bsum, nb);
    scanC<<<nb, 256, 0, stream>>>(partial, bsum, starts, cursor, n, ne);
    scatter_edges<<<(ne + 255) / 256, 256, 0, stream>>>(src, dst, cursor, srcperm, ne);

    node_agg<<<(n + 1) / 2, 256, 0, stream>>>(
        srcperm, starts, a_src, a_dst, (const uint4*)xw, x, bias, gamma, beta, out, n);
}

// Round 7
// 241.929 us; speedup vs baseline: 1.2137x; 1.2137x over previous
//
#include <hip/hip_runtime.h>
#include <hip/hip_bf16.h>
#include <hip/hip_fp16.h>
#include <math.h>

#define ND 128      // feature dim D
#define NH 4        // heads
#define HD 512      // H*D

typedef __attribute__((ext_vector_type(8))) short bf16x8;
typedef __attribute__((ext_vector_type(4))) float f32x4;

__device__ __forceinline__ unsigned pack_bf16(float a, float b) {
    unsigned ua = __float_as_uint(a), ub = __float_as_uint(b);
    ua = (ua + 0x7fffu + ((ua >> 16) & 1u)) >> 16;
    ub = (ub + 0x7fffu + ((ub >> 16) & 1u)) >> 16;
    return ua | (ub << 16);
}
__device__ __forceinline__ unsigned short bf16r(float a) {
    unsigned ua = __float_as_uint(a);
    return (unsigned short)((ua + 0x7fffu + ((ua >> 16) & 1u)) >> 16);
}
__device__ __forceinline__ float bflo(unsigned u) { return __uint_as_float(u << 16); }
__device__ __forceinline__ float bfhi(unsigned u) { return __uint_as_float(u & 0xffff0000u); }

__device__ __forceinline__ unsigned pack_half2(float a, float b) {
    __half ha = __float2half(a), hb = __float2half(b);
    return (unsigned)__half_as_ushort(ha) | ((unsigned)__half_as_ushort(hb) << 16);
}

// ---------------------------------------------------------------------------
// K0: fused W-transpose (blocks [0,256)) + dst histogram (blocks [256, ...)).
// ---------------------------------------------------------------------------
__global__ __launch_bounds__(256) void prep_and_hist(const float* __restrict__ W,
                                                     unsigned short* __restrict__ Wt,
                                                     const int* __restrict__ dst,
                                                     int* __restrict__ cnt, int ne) {
    if (blockIdx.x < 256) {
        int idx = blockIdx.x * 256 + threadIdx.x;   // over 512*128
        int nl = idx >> 7, k = idx & 127;
        Wt[idx] = bf16r(W[(size_t)k * HD + nl]);
    } else {
        int e = (blockIdx.x - 256) * 256 + threadIdx.x;
        if (e < ne) atomicAdd(&cnt[dst[e]], 1);
    }
}

// ---------------------------------------------------------------------------
// K1: MFMA GEMM. Block = 128 rows x 2 heads (looped), 4 waves.
// A staged (and fp32->bf16 packed) ONCE per 2 heads; B restaged per head.
// Epilogue per head: fp32 attention dots from acc; C repacked via LDS (Bs
// region) so xw global stores are coalesced dwordx4.
// ---------------------------------------------------------------------------
__global__ __launch_bounds__(256, 2) void gemm_mfma(
        const float* __restrict__ x, const unsigned short* __restrict__ Wt,
        const float* __restrict__ att_src, const float* __restrict__ att_dst,
        unsigned short* __restrict__ xw, float* __restrict__ a_src,
        float* __restrict__ a_dst, int n) {
    __shared__ char lds[65536];
    char* As = lds;            // 128 rows x 128 k bf16, swizzled
    char* Bs = lds + 32768;    // 128 n   x 128 k bf16, swizzled (reused as Ps)
    const int t = threadIdx.x;
    const int row0 = blockIdx.x * 128;
    const int l = t & 63, w = t >> 6;
    const int eid = l & 15, g = l >> 4;

    // stage A (once)
#pragma unroll
    for (int i = 0; i < 8; ++i) {
        int c = t + i * 256;
        int m = c >> 4, kb = c & 15;
        int row = row0 + m;
        uint4 pk;
        if (row < n) {
            const float4* xp = (const float4*)(x + (size_t)row * ND + kb * 8);
            float4 f0 = xp[0], f1 = xp[1];
            pk.x = pack_bf16(f0.x, f0.y); pk.y = pack_bf16(f0.z, f0.w);
            pk.z = pack_bf16(f1.x, f1.y); pk.w = pack_bf16(f1.z, f1.w);
        } else { pk.x = pk.y = pk.z = pk.w = 0u; }
        *(uint4*)(As + m * 256 + ((kb * 16) ^ ((m & 7) << 4))) = pk;
    }

    for (int hh = 0; hh < 2; ++hh) {
        const int h = blockIdx.y * 2 + hh;
        __syncthreads();   // As ready (iter 0) / Bs-as-Ps consumed (iter 1)
        // stage B for this head
#pragma unroll
        for (int i = 0; i < 8; ++i) {
            int c = t + i * 256;
            int nl = c >> 4, kb = c & 15;
            uint4 pv = *(const uint4*)(Wt + (size_t)(h * 128 + nl) * 128 + kb * 8);
            *(uint4*)(Bs + nl * 256 + ((kb * 16) ^ ((nl & 7) << 4))) = pv;
        }
        __syncthreads();

        f32x4 acc[2][8];
#pragma unroll
        for (int mt = 0; mt < 2; ++mt)
#pragma unroll
            for (int nr = 0; nr < 8; ++nr) acc[mt][nr] = (f32x4){0.f, 0.f, 0.f, 0.f};

        const int swz = (eid & 7) << 4;
#pragma unroll
        for (int ks = 0; ks < 4; ++ks) {
            int koff = (ks * 64 + g * 16) ^ swz;
            bf16x8 a0 = *(const bf16x8*)(As + (w * 32 + eid) * 256 + koff);
            bf16x8 a1 = *(const bf16x8*)(As + (w * 32 + 16 + eid) * 256 + koff);
#pragma unroll
            for (int nr = 0; nr < 8; ++nr) {
                bf16x8 b = *(const bf16x8*)(Bs + (nr * 16 + eid) * 256 + koff);
                acc[0][nr] = __builtin_amdgcn_mfma_f32_16x16x32_bf16(a0, b, acc[0][nr], 0, 0, 0);
                acc[1][nr] = __builtin_amdgcn_mfma_f32_16x16x32_bf16(a1, b, acc[1][nr], 0, 0, 0);
            }
        }

        // attention dots from fp32 acc (register+shfl only)
        float asv[8], adv[8];
#pragma unroll
        for (int nr = 0; nr < 8; ++nr) {
            asv[nr] = att_src[h * ND + nr * 16 + eid];
            adv[nr] = att_dst[h * ND + nr * 16 + eid];
        }
#pragma unroll
        for (int mt = 0; mt < 2; ++mt) {
#pragma unroll
            for (int ri = 0; ri < 4; ++ri) {
                float s = 0.f, d = 0.f;
#pragma unroll
                for (int nr = 0; nr < 8; ++nr) {
                    s += acc[mt][nr][ri] * asv[nr];
                    d += acc[mt][nr][ri] * adv[nr];
                }
#pragma unroll
                for (int off = 1; off < 16; off <<= 1) {
                    s += __shfl_xor(s, off);
                    d += __shfl_xor(d, off);
                }
                int row = row0 + w * 32 + mt * 16 + g * 4 + ri;
                if (eid == 0 && row < n) {
                    a_src[(size_t)row * NH + h] = s;
                    a_dst[(size_t)row * NH + h] = d;
                }
            }
        }

        // repack C tile through Bs-as-Ps -> coalesced bf16 stores
        __syncthreads();   // all waves done reading Bs
        unsigned short* Ps = (unsigned short*)Bs;   // [128 rows][128 cols]
#pragma unroll
        for (int mt = 0; mt < 2; ++mt)
#pragma unroll
            for (int ri = 0; ri < 4; ++ri) {
                int rl = w * 32 + mt * 16 + g * 4 + ri;
#pragma unroll
                for (int nr = 0; nr < 8; ++nr)
                    Ps[rl * 128 + nr * 16 + eid] = bf16r(acc[mt][nr][ri]);
            }
        __syncthreads();
#pragma unroll
        for (int i = 0; i < 8; ++i) {
            int row = i * 16 + (t >> 4);
            int grow = row0 + row;
            if (grow < n) {
                uint4 v = *(const uint4*)(Ps + row * 128 + (t & 15) * 8);
                *(uint4*)(xw + (size_t)grow * HD + h * ND + (t & 15) * 8) = v;
            }
        }
    }
}

// ---------------------------------------------------------------------------
// Counting-sort scans.
// ---------------------------------------------------------------------------
__global__ __launch_bounds__(256) void scanA(const int* __restrict__ cnt,
                                             int* __restrict__ partial,
                                             int* __restrict__ bsum, int n) {
    __shared__ int sh[256];
    int gid = blockIdx.x * 256 + threadIdx.x;
    int v = (gid < n) ? cnt[gid] : 0;
    int val = v;
    sh[threadIdx.x] = val;
    __syncthreads();
#pragma unroll
    for (int off = 1; off < 256; off <<= 1) {
        int add = (threadIdx.x >= off) ? sh[threadIdx.x - off] : 0;
        __syncthreads();
        val += add;
        sh[threadIdx.x] = val;
        __syncthreads();
    }
    if (gid < n) partial[gid] = val - v;
    if (threadIdx.x == 255) bsum[blockIdx.x] = val;
}

__global__ __launch_bounds__(256) void scanB(int* __restrict__ bsum, int nb) {
    __shared__ int sh[256];
    int t = threadIdx.x;
    int v = (t < nb) ? bsum[t] : 0;
    int val = v;
    sh[t] = val;
    __syncthreads();
#pragma unroll
    for (int off = 1; off < 256; off <<= 1) {
        int add = (t >= off) ? sh[t - off] : 0;
        __syncthreads();
        val += add;
        sh[t] = val;
        __syncthreads();
    }
    if (t < nb) bsum[t] = val - v;
}

__global__ __launch_bounds__(256) void scanC(const int* __restrict__ partial,
                                             const int* __restrict__ bsum,
                                             int* __restrict__ starts,
                                             int* __restrict__ cursor, int n, int ne) {
    int gid = blockIdx.x * 256 + threadIdx.x;
    if (gid < n) {
        int s = partial[gid] + bsum[blockIdx.x];
        starts[gid] = s;
        cursor[gid] = s;
    }
    if (gid == 0) starts[n] = ne;
}

// ---------------------------------------------------------------------------
// K_scatter: permute edges into dst-segment order AND precompute the 4 head
// weights exp(lrelu(a_src[src]+a_dst[dst])) as fp16 — one 16B record per edge:
// {src, w01, w23, pad}. Removes the random a_src gather + exp from node_agg.
// (attn = w/sum(w): fp16 quantization cancels in the ratio.)
// ---------------------------------------------------------------------------
__global__ __launch_bounds__(256) void scatter_edges_w(const int* __restrict__ src,
                                                       const int* __restrict__ dst,
                                                       const float* __restrict__ a_src,
                                                       const float* __restrict__ a_dst,
                                                       int* __restrict__ cursor,
                                                       uint4* __restrict__ eperm, int ne) {
    int e = blockIdx.x * 256 + threadIdx.x;
    if (e < ne) {
        int s = src[e], t = dst[e];
        float4 as = *(const float4*)(a_src + (size_t)s * NH);
        float4 ad = *(const float4*)(a_dst + (size_t)t * NH);
        float A0 = as.x + ad.x, A1 = as.y + ad.y, A2 = as.z + ad.z, A3 = as.w + ad.w;
        A0 = (A0 > 0.f) ? A0 : 0.2f * A0;
        A1 = (A1 > 0.f) ? A1 : 0.2f * A1;
        A2 = (A2 > 0.f) ? A2 : 0.2f * A2;
        A3 = (A3 > 0.f) ? A3 : 0.2f * A3;
        float e0 = expf(A0), e1 = expf(A1), e2 = expf(A2), e3 = expf(A3);
        int pos = atomicAdd(&cursor[t], 1);
        uint4 ev;
        ev.x = (unsigned)s;
        ev.y = pack_half2(e0, e1);
        ev.z = pack_half2(e2, e3);
        ev.w = 0u;
        eperm[pos] = ev;
    }
}

// ---------------------------------------------------------------------------
// K_agg: one wave per dst node (R3 structure: 36 VGPR, high occupancy).
// 16-edge chunks; lane = (head=l>>4, slot=l&15). Per chunk: one contiguous
// 16B eperm read/lane (src + precomputed fp16 weights) -> shfl -> 1KB xw
// gather -> FMA. Deferred softmax normalization; fused mean+bias+LN+GELU+res.
// ---------------------------------------------------------------------------
#define ACC8(vv, ww)                                                      \
    acc[0] = fmaf(ww, bflo(vv.x), acc[0]);                                \
    acc[1] = fmaf(ww, bfhi(vv.x), acc[1]);                                \
    acc[2] = fmaf(ww, bflo(vv.y), acc[2]);                                \
    acc[3] = fmaf(ww, bfhi(vv.y), acc[3]);                                \
    acc[4] = fmaf(ww, bflo(vv.z), acc[4]);                                \
    acc[5] = fmaf(ww, bfhi(vv.z), acc[5]);                                \
    acc[6] = fmaf(ww, bflo(vv.w), acc[6]);                                \
    acc[7] = fmaf(ww, bfhi(vv.w), acc[7]);

__global__ __launch_bounds__(256) void node_agg(const uint4* __restrict__ eperm,
                                                const int* __restrict__ starts,
                                                const uint4* __restrict__ xw,
                                                const float* __restrict__ x,
                                                const float* __restrict__ bias,
                                                const float* __restrict__ gamma,
                                                const float* __restrict__ beta,
                                                float* __restrict__ out, int n) {
    int node = (blockIdx.x * 256 + threadIdx.x) >> 6;
    int lane = threadIdx.x & 63;
    if (node >= n) return;
    const int hgrp = lane >> 4;   // my head
    const int eid = lane & 15;    // my edge slot / feature octet
    const int hb = hgrp << 4;

    int s0 = starts[node], s1 = starts[node + 1];

    float den = 0.f;
    float acc[8];
#pragma unroll
    for (int j = 0; j < 8; ++j) acc[j] = 0.f;

    for (int base = s0; base < s1; base += 16) {
        int rem = s1 - base; if (rem > 16) rem = 16;
        int sl = 0; float em = 0.f;
        if (eid < rem) {
            uint4 ev = eperm[base + eid];
            sl = (int)ev.x;
            unsigned wb = (hgrp & 2) ? ev.z : ev.y;
            unsigned short hbits = (hgrp & 1) ? (unsigned short)(wb >> 16)
                                              : (unsigned short)(wb & 0xffffu);
            em = __half2float(__ushort_as_half(hbits));
        }
        den += em;

        int jj = 0;
        for (; jj + 4 <= rem; jj += 4) {
            int t0 = __shfl(sl, jj),     t1 = __shfl(sl, jj + 1);
            int t2 = __shfl(sl, jj + 2), t3 = __shfl(sl, jj + 3);
            uint4 v0 = xw[(size_t)t0 * 64 + lane];
            uint4 v1 = xw[(size_t)t1 * 64 + lane];
            uint4 v2 = xw[(size_t)t2 * 64 + lane];
            uint4 v3 = xw[(size_t)t3 * 64 + lane];
            float w0 = __shfl(em, hb + jj);
            float w1 = __shfl(em, hb + jj + 1);
            float w2 = __shfl(em, hb + jj + 2);
            float w3 = __shfl(em, hb + jj + 3);
            ACC8(v0, w0); ACC8(v1, w1); ACC8(v2, w2); ACC8(v3, w3);
        }
        for (; jj < rem; ++jj) {
            int ts = __shfl(sl, jj);
            uint4 v = xw[(size_t)ts * 64 + lane];
            float ww = __shfl(em, hb + jj);
            ACC8(v, ww);
        }
    }

    // per-head denominator: reduce over the 16 slots in my head group
#pragma unroll
    for (int off = 1; off < 16; off <<= 1) den += __shfl_xor(den, off);
    float imy = (den > 0.f) ? 0.25f / den : 0.f;

    float v[8];
#pragma unroll
    for (int j = 0; j < 8; ++j) {
        v[j] = acc[j] * imy;
        v[j] += __shfl_xor(v[j], 16);   // sum over heads
        v[j] += __shfl_xor(v[j], 32);
    }

    const float4* bp = (const float4*)(bias + eid * 8);
    float4 b0 = bp[0], b1 = bp[1];
    v[0] += b0.x; v[1] += b0.y; v[2] += b0.z; v[3] += b0.w;
    v[4] += b1.x; v[5] += b1.y; v[6] += b1.z; v[7] += b1.w;

    // LayerNorm over 128 features = 16 lane-groups x 8 slots (replicated 4x)
    float s = 0.f, s2 = 0.f;
#pragma unroll
    for (int j = 0; j < 8; ++j) { s += v[j]; s2 += v[j] * v[j]; }
#pragma unroll
    for (int off = 1; off < 16; off <<= 1) {
        s += __shfl_xor(s, off);
        s2 += __shfl_xor(s2, off);
    }
    float mu = s * (1.0f / ND);
    float var = s2 * (1.0f / ND) - mu * mu;
    var = fmaxf(var, 0.0f);
    float inv = rsqrtf(var + 1e-5f);

    const float4* gp = (const float4*)(gamma + eid * 8);
    const float4* btp = (const float4*)(beta + eid * 8);
    float4 g0 = gp[0], g1 = gp[1];
    float4 t0 = btp[0], t1 = btp[1];
    float gm[8] = {g0.x, g0.y, g0.z, g0.w, g1.x, g1.y, g1.z, g1.w};
    float bt[8] = {t0.x, t0.y, t0.z, t0.w, t1.x, t1.y, t1.z, t1.w};

    float y[8];
#pragma unroll
    for (int j = 0; j < 8; ++j) {
        float yn = (v[j] - mu) * inv * gm[j] + bt[j];
        y[j] = 0.5f * yn * (1.0f + erff(yn * 0.70710678118654752f));
    }

    if (lane < 16) {   // one replica writes; +residual
        const float4* xp = (const float4*)(x + (size_t)node * ND + eid * 8);
        float4 r0 = xp[0], r1 = xp[1];
        float4 o0 = {y[0] + r0.x, y[1] + r0.y, y[2] + r0.z, y[3] + r0.w};
        float4 o1 = {y[4] + r1.x, y[5] + r1.y, y[6] + r1.z, y[7] + r1.w};
        float4* op = (float4*)(out + (size_t)node * ND + eid * 8);
        op[0] = o0; op[1] = o1;
    }
}

// ---------------------------------------------------------------------------
extern "C" void kernel_launch(void* const* d_in, const int* in_sizes, int n_in,
                              void* d_out, int out_size, void* d_ws, size_t ws_size,
                              hipStream_t stream) {
    const float* x       = (const float*)d_in[0];
    const int*   edge    = (const int*)d_in[1];   // [2, E]: src row then dst row
    const float* W       = (const float*)d_in[2];
    const float* att_src = (const float*)d_in[3];
    const float* att_dst = (const float*)d_in[4];
    const float* bias    = (const float*)d_in[5];
    const float* gamma   = (const float*)d_in[6];
    const float* beta    = (const float*)d_in[7];
    float* out = (float*)d_out;

    const int n  = in_sizes[0] / ND;   // 50000
    const int ne = in_sizes[1] / 2;    // 800000
    const int* src = edge;
    const int* dst = edge + ne;

    const int nb = (n + 255) / 256;

    char* wsp = (char*)d_ws;
    unsigned short* xw = (unsigned short*)wsp;  wsp += (size_t)n * HD * sizeof(short);
    unsigned short* Wt = (unsigned short*)wsp;  wsp += (size_t)HD * ND * sizeof(short);
    float* a_src   = (float*)wsp;               wsp += (size_t)n * NH * sizeof(float);
    float* a_dst   = (float*)wsp;               wsp += (size_t)n * NH * sizeof(float);
    uint4* eperm   = (uint4*)wsp;               wsp += (size_t)ne * sizeof(uint4);
    int*   cnt     = (int*)wsp;                 wsp += (size_t)n * sizeof(int);
    int*   partial = (int*)wsp;                 wsp += (size_t)n * sizeof(int);
    int*   bsum    = (int*)wsp;                 wsp += 256 * sizeof(int);
    int*   starts  = (int*)wsp;                 wsp += (size_t)(n + 1) * sizeof(int);
    int*   cursor  = (int*)wsp;                 wsp += (size_t)n * sizeof(int);

    hipMemsetAsync(cnt, 0, (size_t)n * sizeof(int), stream);

    prep_and_hist<<<256 + (ne + 255) / 256, 256, 0, stream>>>(W, Wt, dst, cnt, ne);

    dim3 ggrid((n + 127) / 128, 2);
    gemm_mfma<<<ggrid, 256, 0, stream>>>(x, Wt, att_src, att_dst, xw, a_src, a_dst, n);

    scanA<<<nb, 256, 0, stream>>>(cnt, partial, bsum, n);
    scanB<<<1, 256, 0, stream>>>(bsum, nb);
    scanC<<<nb, 256, 0, stream>>>(partial, bsum, starts, cursor, n, ne);
    scatter_edges_w<<<(ne + 255) / 256, 256, 0, stream>>>(src, dst, a_src, a_dst,
                                                          cursor, eperm, ne);

    node_agg<<<((size_t)n * 64 + 255) / 256, 256, 0, stream>>>(
        eperm, starts, (const uint4*)xw, x, bias, gamma, beta, out, n);
}

// Round 8
// 239.186 us; speedup vs baseline: 1.2277x; 1.0115x over previous
//
#include <hip/hip_runtime.h>
#include <hip/hip_bf16.h>
#include <hip/hip_fp16.h>
#include <math.h>

#define ND 128      // feature dim D
#define NH 4        // heads
#define HD 512      // H*D

typedef __attribute__((ext_vector_type(8))) short bf16x8;
typedef __attribute__((ext_vector_type(4))) float f32x4;

__device__ __forceinline__ unsigned pack_bf16(float a, float b) {
    unsigned ua = __float_as_uint(a), ub = __float_as_uint(b);
    ua = (ua + 0x7fffu + ((ua >> 16) & 1u)) >> 16;
    ub = (ub + 0x7fffu + ((ub >> 16) & 1u)) >> 16;
    return ua | (ub << 16);
}
__device__ __forceinline__ unsigned short bf16r(float a) {
    unsigned ua = __float_as_uint(a);
    return (unsigned short)((ua + 0x7fffu + ((ua >> 16) & 1u)) >> 16);
}
__device__ __forceinline__ float bflo(unsigned u) { return __uint_as_float(u << 16); }
__device__ __forceinline__ float bfhi(unsigned u) { return __uint_as_float(u & 0xffff0000u); }

__device__ __forceinline__ unsigned pack_half2(float a, float b) {
    __half ha = __float2half(a), hb = __float2half(b);
    return (unsigned)__half_as_ushort(ha) | ((unsigned)__half_as_ushort(hb) << 16);
}

// ---------------------------------------------------------------------------
// K0: fused W-transpose (blocks [0,256)) + dst histogram (blocks [256, ...)).
// ---------------------------------------------------------------------------
__global__ __launch_bounds__(256) void prep_and_hist(const float* __restrict__ W,
                                                     unsigned short* __restrict__ Wt,
                                                     const int* __restrict__ dst,
                                                     int* __restrict__ cnt, int ne) {
    if (blockIdx.x < 256) {
        int idx = blockIdx.x * 256 + threadIdx.x;   // over 512*128
        int nl = idx >> 7, k = idx & 127;
        Wt[idx] = bf16r(W[(size_t)k * HD + nl]);
    } else {
        int e = (blockIdx.x - 256) * 256 + threadIdx.x;
        if (e < ne) atomicAdd(&cnt[dst[e]], 1);
    }
}

// ---------------------------------------------------------------------------
// K1: MFMA GEMM. Block = 128 rows x 2 heads (looped), 4 waves.
// A staged (and fp32->bf16 packed) ONCE per 2 heads; B restaged per head.
// Epilogue per head: fp32 attention dots; C repacked via LDS for coalesced
// dwordx4 xw stores.
// ---------------------------------------------------------------------------
__global__ __launch_bounds__(256, 2) void gemm_mfma(
        const float* __restrict__ x, const unsigned short* __restrict__ Wt,
        const float* __restrict__ att_src, const float* __restrict__ att_dst,
        unsigned short* __restrict__ xw, float* __restrict__ a_src,
        float* __restrict__ a_dst, int n) {
    __shared__ char lds[65536];
    char* As = lds;            // 128 rows x 128 k bf16, swizzled
    char* Bs = lds + 32768;    // 128 n   x 128 k bf16, swizzled (reused as Ps)
    const int t = threadIdx.x;
    const int row0 = blockIdx.x * 128;
    const int l = t & 63, w = t >> 6;
    const int eid = l & 15, g = l >> 4;

    // stage A (once)
#pragma unroll
    for (int i = 0; i < 8; ++i) {
        int c = t + i * 256;
        int m = c >> 4, kb = c & 15;
        int row = row0 + m;
        uint4 pk;
        if (row < n) {
            const float4* xp = (const float4*)(x + (size_t)row * ND + kb * 8);
            float4 f0 = xp[0], f1 = xp[1];
            pk.x = pack_bf16(f0.x, f0.y); pk.y = pack_bf16(f0.z, f0.w);
            pk.z = pack_bf16(f1.x, f1.y); pk.w = pack_bf16(f1.z, f1.w);
        } else { pk.x = pk.y = pk.z = pk.w = 0u; }
        *(uint4*)(As + m * 256 + ((kb * 16) ^ ((m & 7) << 4))) = pk;
    }

    for (int hh = 0; hh < 2; ++hh) {
        const int h = blockIdx.y * 2 + hh;
        __syncthreads();   // As ready (iter 0) / Bs-as-Ps consumed (iter 1)
        // stage B for this head
#pragma unroll
        for (int i = 0; i < 8; ++i) {
            int c = t + i * 256;
            int nl = c >> 4, kb = c & 15;
            uint4 pv = *(const uint4*)(Wt + (size_t)(h * 128 + nl) * 128 + kb * 8);
            *(uint4*)(Bs + nl * 256 + ((kb * 16) ^ ((nl & 7) << 4))) = pv;
        }
        __syncthreads();

        f32x4 acc[2][8];
#pragma unroll
        for (int mt = 0; mt < 2; ++mt)
#pragma unroll
            for (int nr = 0; nr < 8; ++nr) acc[mt][nr] = (f32x4){0.f, 0.f, 0.f, 0.f};

        const int swz = (eid & 7) << 4;
#pragma unroll
        for (int ks = 0; ks < 4; ++ks) {
            int koff = (ks * 64 + g * 16) ^ swz;
            bf16x8 a0 = *(const bf16x8*)(As + (w * 32 + eid) * 256 + koff);
            bf16x8 a1 = *(const bf16x8*)(As + (w * 32 + 16 + eid) * 256 + koff);
#pragma unroll
            for (int nr = 0; nr < 8; ++nr) {
                bf16x8 b = *(const bf16x8*)(Bs + (nr * 16 + eid) * 256 + koff);
                acc[0][nr] = __builtin_amdgcn_mfma_f32_16x16x32_bf16(a0, b, acc[0][nr], 0, 0, 0);
                acc[1][nr] = __builtin_amdgcn_mfma_f32_16x16x32_bf16(a1, b, acc[1][nr], 0, 0, 0);
            }
        }

        // attention dots from fp32 acc (register+shfl only)
        float asv[8], adv[8];
#pragma unroll
        for (int nr = 0; nr < 8; ++nr) {
            asv[nr] = att_src[h * ND + nr * 16 + eid];
            adv[nr] = att_dst[h * ND + nr * 16 + eid];
        }
#pragma unroll
        for (int mt = 0; mt < 2; ++mt) {
#pragma unroll
            for (int ri = 0; ri < 4; ++ri) {
                float s = 0.f, d = 0.f;
#pragma unroll
                for (int nr = 0; nr < 8; ++nr) {
                    s += acc[mt][nr][ri] * asv[nr];
                    d += acc[mt][nr][ri] * adv[nr];
                }
#pragma unroll
                for (int off = 1; off < 16; off <<= 1) {
                    s += __shfl_xor(s, off);
                    d += __shfl_xor(d, off);
                }
                int row = row0 + w * 32 + mt * 16 + g * 4 + ri;
                if (eid == 0 && row < n) {
                    a_src[(size_t)row * NH + h] = s;
                    a_dst[(size_t)row * NH + h] = d;
                }
            }
        }

        // repack C tile through Bs-as-Ps -> coalesced bf16 stores
        __syncthreads();   // all waves done reading Bs
        unsigned short* Ps = (unsigned short*)Bs;   // [128 rows][128 cols]
#pragma unroll
        for (int mt = 0; mt < 2; ++mt)
#pragma unroll
            for (int ri = 0; ri < 4; ++ri) {
                int rl = w * 32 + mt * 16 + g * 4 + ri;
#pragma unroll
                for (int nr = 0; nr < 8; ++nr)
                    Ps[rl * 128 + nr * 16 + eid] = bf16r(acc[mt][nr][ri]);
            }
        __syncthreads();
#pragma unroll
        for (int i = 0; i < 8; ++i) {
            int row = i * 16 + (t >> 4);
            int grow = row0 + row;
            if (grow < n) {
                uint4 v = *(const uint4*)(Ps + row * 128 + (t & 15) * 8);
                *(uint4*)(xw + (size_t)grow * HD + h * ND + (t & 15) * 8) = v;
            }
        }
    }
}

// ---------------------------------------------------------------------------
// Counting-sort scans. scanA: per-block exclusive + block sums.
// scanBC: every block redundantly scans the <=256 block sums in LDS (cheap),
// then applies its offset — deletes the separate scanB launch.
// ---------------------------------------------------------------------------
__global__ __launch_bounds__(256) void scanA(const int* __restrict__ cnt,
                                             int* __restrict__ partial,
                                             int* __restrict__ bsum, int n) {
    __shared__ int sh[256];
    int gid = blockIdx.x * 256 + threadIdx.x;
    int v = (gid < n) ? cnt[gid] : 0;
    int val = v;
    sh[threadIdx.x] = val;
    __syncthreads();
#pragma unroll
    for (int off = 1; off < 256; off <<= 1) {
        int add = (threadIdx.x >= off) ? sh[threadIdx.x - off] : 0;
        __syncthreads();
        val += add;
        sh[threadIdx.x] = val;
        __syncthreads();
    }
    if (gid < n) partial[gid] = val - v;
    if (threadIdx.x == 255) bsum[blockIdx.x] = val;
}

__global__ __launch_bounds__(256) void scanBC(const int* __restrict__ partial,
                                              const int* __restrict__ bsum,
                                              int* __restrict__ starts,
                                              int* __restrict__ cursor,
                                              int n, int ne, int nb) {
    __shared__ int sh[256];
    int t = threadIdx.x;
    int v = (t < nb) ? bsum[t] : 0;
    int val = v;
    sh[t] = val;
    __syncthreads();
#pragma unroll
    for (int off = 1; off < 256; off <<= 1) {
        int add = (t >= off) ? sh[t - off] : 0;
        __syncthreads();
        val += add;
        sh[t] = val;
        __syncthreads();
    }
    int myoff = (blockIdx.x == 0) ? 0 : sh[blockIdx.x - 1];
    int gid = blockIdx.x * 256 + t;
    if (gid < n) {
        int s = partial[gid] + myoff;
        starts[gid] = s;
        cursor[gid] = s;
    }
    if (gid == 0) starts[n] = ne;
}

// ---------------------------------------------------------------------------
// K_scatter: permute edges into dst-segment order, precompute 4 head weights
// as fp16: one 16B record per edge {src, w01, w23, pad}.
// ---------------------------------------------------------------------------
__global__ __launch_bounds__(256) void scatter_edges_w(const int* __restrict__ src,
                                                       const int* __restrict__ dst,
                                                       const float* __restrict__ a_src,
                                                       const float* __restrict__ a_dst,
                                                       int* __restrict__ cursor,
                                                       uint4* __restrict__ eperm, int ne) {
    int e = blockIdx.x * 256 + threadIdx.x;
    if (e < ne) {
        int s = src[e], t = dst[e];
        float4 as = *(const float4*)(a_src + (size_t)s * NH);
        float4 ad = *(const float4*)(a_dst + (size_t)t * NH);
        float A0 = as.x + ad.x, A1 = as.y + ad.y, A2 = as.z + ad.z, A3 = as.w + ad.w;
        A0 = (A0 > 0.f) ? A0 : 0.2f * A0;
        A1 = (A1 > 0.f) ? A1 : 0.2f * A1;
        A2 = (A2 > 0.f) ? A2 : 0.2f * A2;
        A3 = (A3 > 0.f) ? A3 : 0.2f * A3;
        float e0 = expf(A0), e1 = expf(A1), e2 = expf(A2), e3 = expf(A3);
        int pos = atomicAdd(&cursor[t], 1);
        uint4 ev;
        ev.x = (unsigned)s;
        ev.y = pack_half2(e0, e1);
        ev.z = pack_half2(e2, e3);
        ev.w = 0u;
        eperm[pos] = ev;
    }
}

// ---------------------------------------------------------------------------
// K_agg v2: TWO waves per node, split by HEAD PAIR (wave q owns heads 2q,2q+1).
// Each wave gathers a contiguous 512B half-row per edge (8B/lane, lane =
// (head-of-pair = l>>5, dim-quad/edge-slot = l&31)), 32-edge chunks.
// acc is 4 floats/lane (half of R7) -> low VGPR, high occupancy, 2x waves
// for latency hiding. Cross-wave head-sum via 1KB LDS; wave 0 does
// bias+LN+GELU+residual epilogue on lanes 0..31.
// ---------------------------------------------------------------------------
#define ACC4(vv, ww)                                                      \
    acc[0] = fmaf(ww, bflo(vv.x), acc[0]);                                \
    acc[1] = fmaf(ww, bfhi(vv.x), acc[1]);                                \
    acc[2] = fmaf(ww, bflo(vv.y), acc[2]);                                \
    acc[3] = fmaf(ww, bfhi(vv.y), acc[3]);

__global__ __launch_bounds__(256) void node_agg(const uint4* __restrict__ eperm,
                                                const int* __restrict__ starts,
                                                const uint2* __restrict__ xw2,
                                                const float* __restrict__ x,
                                                const float* __restrict__ bias,
                                                const float* __restrict__ gamma,
                                                const float* __restrict__ beta,
                                                float* __restrict__ out, int n) {
    __shared__ float comb[2][32][4];   // wave-1 partials per node slot

    const int wib = threadIdx.x >> 6;       // wave in block (0..3)
    const int lane = threadIdx.x & 63;
    const int pairslot = wib >> 1;          // node slot in block (0/1)
    const int q = wib & 1;                  // head-pair (0: heads 0,1; 1: heads 2,3)
    const int node = blockIdx.x * 2 + pairslot;
    const int hsel = lane >> 5;             // which head of my pair
    const int slot = lane & 31;             // edge slot == dim quad
    const int habs = q * 2 + hsel;          // absolute head
    const int hb = hsel << 5;

    const bool alive = (node < n);
    int s0 = 0, s1 = 0;
    if (alive) { s0 = starts[node]; s1 = starts[node + 1]; }

    float den = 0.f;
    float acc[4] = {0.f, 0.f, 0.f, 0.f};

    for (int base = s0; base < s1; base += 32) {
        int rem = s1 - base; if (rem > 32) rem = 32;
        int sl = 0; float em = 0.f;
        if (slot < rem) {
            uint4 ev = eperm[base + slot];
            sl = (int)ev.x;
            unsigned wb2 = (habs & 2) ? ev.z : ev.y;
            unsigned short hbits = (habs & 1) ? (unsigned short)(wb2 >> 16)
                                              : (unsigned short)(wb2 & 0xffffu);
            em = __half2float(__ushort_as_half(hbits));
        }
        den += em;

        int jj = 0;
        for (; jj + 4 <= rem; jj += 4) {
            int t0 = __shfl(sl, jj),     t1 = __shfl(sl, jj + 1);
            int t2 = __shfl(sl, jj + 2), t3 = __shfl(sl, jj + 3);
            uint2 v0 = xw2[(size_t)t0 * 128 + habs * 32 + slot];
            uint2 v1 = xw2[(size_t)t1 * 128 + habs * 32 + slot];
            uint2 v2 = xw2[(size_t)t2 * 128 + habs * 32 + slot];
            uint2 v3 = xw2[(size_t)t3 * 128 + habs * 32 + slot];
            float w0 = __shfl(em, hb + jj);
            float w1 = __shfl(em, hb + jj + 1);
            float w2 = __shfl(em, hb + jj + 2);
            float w3 = __shfl(em, hb + jj + 3);
            ACC4(v0, w0); ACC4(v1, w1); ACC4(v2, w2); ACC4(v3, w3);
        }
        for (; jj < rem; ++jj) {
            int ts = __shfl(sl, jj);
            uint2 v = xw2[(size_t)ts * 128 + habs * 32 + slot];
            float ww = __shfl(em, hb + jj);
            ACC4(v, ww);
        }
    }

    // per-head denominator: reduce over the 32 slots of my half-wave
#pragma unroll
    for (int off = 1; off < 32; off <<= 1) den += __shfl_xor(den, off);
    float imy = (den > 0.f) ? 0.25f / den : 0.f;

    float v[4];
#pragma unroll
    for (int j = 0; j < 4; ++j) {
        v[j] = acc[j] * imy;
        v[j] += __shfl_xor(v[j], 32);   // sum my head pair
    }

    // cross-wave (head pair 0+1 vs 2+3) combine via LDS
    if (q == 1 && lane < 32) {
#pragma unroll
        for (int j = 0; j < 4; ++j) comb[pairslot][slot][j] = v[j];
    }
    __syncthreads();
    if (q == 1 || !alive || lane >= 32) return;
#pragma unroll
    for (int j = 0; j < 4; ++j) v[j] += comb[pairslot][slot][j];

    // + bias
    float4 bv = *(const float4*)(bias + slot * 4);
    v[0] += bv.x; v[1] += bv.y; v[2] += bv.z; v[3] += bv.w;

    // LayerNorm over 128 = 32 lanes x 4
    float s = v[0] + v[1] + v[2] + v[3];
    float s2 = v[0] * v[0] + v[1] * v[1] + v[2] * v[2] + v[3] * v[3];
#pragma unroll
    for (int off = 1; off < 32; off <<= 1) {
        s += __shfl_xor(s, off);
        s2 += __shfl_xor(s2, off);
    }
    float mu = s * (1.0f / ND);
    float var = s2 * (1.0f / ND) - mu * mu;
    var = fmaxf(var, 0.0f);
    float inv = rsqrtf(var + 1e-5f);

    float4 gv = *(const float4*)(gamma + slot * 4);
    float4 tv = *(const float4*)(beta + slot * 4);
    float gm[4] = {gv.x, gv.y, gv.z, gv.w};
    float bt[4] = {tv.x, tv.y, tv.z, tv.w};

    float4 rv = *(const float4*)(x + (size_t)node * ND + slot * 4);
    float rs[4] = {rv.x, rv.y, rv.z, rv.w};

    float y[4];
#pragma unroll
    for (int j = 0; j < 4; ++j) {
        float yn = (v[j] - mu) * inv * gm[j] + bt[j];
        y[j] = 0.5f * yn * (1.0f + erff(yn * 0.70710678118654752f)) + rs[j];
    }
    float4 ov = {y[0], y[1], y[2], y[3]};
    *(float4*)(out + (size_t)node * ND + slot * 4) = ov;
}

// ---------------------------------------------------------------------------
extern "C" void kernel_launch(void* const* d_in, const int* in_sizes, int n_in,
                              void* d_out, int out_size, void* d_ws, size_t ws_size,
                              hipStream_t stream) {
    const float* x       = (const float*)d_in[0];
    const int*   edge    = (const int*)d_in[1];   // [2, E]: src row then dst row
    const float* W       = (const float*)d_in[2];
    const float* att_src = (const float*)d_in[3];
    const float* att_dst = (const float*)d_in[4];
    const float* bias    = (const float*)d_in[5];
    const float* gamma   = (const float*)d_in[6];
    const float* beta    = (const float*)d_in[7];
    float* out = (float*)d_out;

    const int n  = in_sizes[0] / ND;   // 50000
    const int ne = in_sizes[1] / 2;    // 800000
    const int* src = edge;
    const int* dst = edge + ne;

    const int nb = (n + 255) / 256;    // 196 (<256)

    char* wsp = (char*)d_ws;
    unsigned short* xw = (unsigned short*)wsp;  wsp += (size_t)n * HD * sizeof(short);
    unsigned short* Wt = (unsigned short*)wsp;  wsp += (size_t)HD * ND * sizeof(short);
    float* a_src   = (float*)wsp;               wsp += (size_t)n * NH * sizeof(float);
    float* a_dst   = (float*)wsp;               wsp += (size_t)n * NH * sizeof(float);
    uint4* eperm   = (uint4*)wsp;               wsp += (size_t)ne * sizeof(uint4);
    int*   cnt     = (int*)wsp;                 wsp += (size_t)n * sizeof(int);
    int*   partial = (int*)wsp;                 wsp += (size_t)n * sizeof(int);
    int*   bsum    = (int*)wsp;                 wsp += 256 * sizeof(int);
    int*   starts  = (int*)wsp;                 wsp += (size_t)(n + 1) * sizeof(int);
    int*   cursor  = (int*)wsp;                 wsp += (size_t)n * sizeof(int);

    hipMemsetAsync(cnt, 0, (size_t)n * sizeof(int), stream);

    prep_and_hist<<<256 + (ne + 255) / 256, 256, 0, stream>>>(W, Wt, dst, cnt, ne);

    dim3 ggrid((n + 127) / 128, 2);
    gemm_mfma<<<ggrid, 256, 0, stream>>>(x, Wt, att_src, att_dst, xw, a_src, a_dst, n);

    scanA<<<nb, 256, 0, stream>>>(cnt, partial, bsum, n);
    scanBC<<<nb, 256, 0, stream>>>(partial, bsum, starts, cursor, n, ne, nb);
    scatter_edges_w<<<(ne + 255) / 256, 256, 0, stream>>>(src, dst, a_src, a_dst,
                                                          cursor, eperm, ne);

    node_agg<<<(n + 1) / 2, 256, 0, stream>>>(
        eperm, starts, (const uint2*)xw, x, bias, gamma, beta, out, n);
}